// Round 1
// baseline (626.921 us; speedup 1.0000x reference)
//
#include <hip/hip_runtime.h>

// GameURMAttention: x[65536,512] -> QKV -> 8-head SDPA (S=16,D=64) -> out-proj.
// k0: weights -> bf16 in ws (if ws big enough)
// k1: fused QKV+attention, writes attn (fp32) into d_out
// k2: out = attn @ w_o^T, in-place on d_out (block owns full rows -> race-free)

#define NROWS 65536
#define HID   512
#define NHEAD 8
#define HDIM  64

typedef __attribute__((ext_vector_type(4))) float  float4v;
typedef __attribute__((ext_vector_type(8))) short  short8;
typedef __attribute__((ext_vector_type(4))) short  short4v;
typedef __attribute__((ext_vector_type(8))) __bf16 bf16x8;

static __device__ __forceinline__ short bf16rne(float f) {
    union { float f; unsigned u; } v; v.f = f;
    unsigned u = v.u + 0x7FFFu + ((v.u >> 16) & 1u);
    return (short)(u >> 16);
}

static __device__ __forceinline__ void cvt8_store(short* dst, const float* src) {
    float4v a = *(const float4v*)src;
    float4v b = *(const float4v*)(src + 4);
    short8 o;
    o[0] = bf16rne(a[0]); o[1] = bf16rne(a[1]); o[2] = bf16rne(a[2]); o[3] = bf16rne(a[3]);
    o[4] = bf16rne(b[0]); o[5] = bf16rne(b[1]); o[6] = bf16rne(b[2]); o[7] = bf16rne(b[3]);
    *(short8*)dst = o;
}

static __device__ __forceinline__ float4v mfma16(short8 a, short8 b, float4v c) {
    union { short8 s; bf16x8 v; } ua, ub;
    ua.s = a; ub.s = b;
    return __builtin_amdgcn_mfma_f32_16x16x32_bf16(ua.v, ub.v, c, 0, 0, 0);
}

// ---------------- k0: weight conversion to bf16 ----------------
// dst layout: [0 .. 786431] = w_qkv bf16 (row-major 1536x512), then 262144 of w_o.
__global__ void cvt_w_kernel(const float* __restrict__ wq, const float* __restrict__ wo,
                             short* __restrict__ dst) {
    int i = (blockIdx.x * 256 + threadIdx.x) * 4;
    const float* src = (i < 786432) ? (wq + i) : (wo + (i - 786432));
    float4v v = *(const float4v*)src;
    short4v o;
    o[0] = bf16rne(v[0]); o[1] = bf16rne(v[1]); o[2] = bf16rne(v[2]); o[3] = bf16rne(v[3]);
    *(short4v*)&dst[i] = o;
}

// ---------------- k1: fused QKV + attention ----------------
// grid 1024 x 256 threads (4 waves). Mtile=64 rows = 4 batches (SEQ=16).
// LDS: staging {X 64x72, W 192x72} unioned with attn {Q 64x72, K 64x72, VT 64x88, P 4x16x40}.
__global__ __launch_bounds__(256, 4)
void qkv_attn_kernel(const float* __restrict__ x, const float* __restrict__ wq_f,
                     const short* __restrict__ wq_b, const int use_bf,
                     float* __restrict__ out) {
    __shared__ __align__(16) union {
        struct { short x[64 * 72]; short w[192 * 72]; } st;                     // 36864 B
        struct { short q[64 * 72]; short k[64 * 72]; short vt[64 * 88]; short p[4 * 16 * 40]; } at; // 32256 B
    } L;

    const int tid  = threadIdx.x;
    const int wave = tid >> 6;
    const int lane = tid & 63;
    const int ln   = lane & 15;          // frag row/col within 16
    const int q8   = (lane >> 4) * 8;    // A/B frag k-offset
    const int qrow = (lane >> 4) * 4;    // C frag row base
    const int m0   = blockIdx.x * 64;

    for (int h = 0; h < NHEAD; ++h) {
        float4v acc[4][3];
        #pragma unroll
        for (int fr = 0; fr < 4; ++fr)
            #pragma unroll
            for (int fc = 0; fc < 3; ++fc)
                acc[fr][fc] = (float4v){0.f, 0.f, 0.f, 0.f};

        // ---- GEMM: QKV_h (64x192) = Xtile (64x512) @ Wh^T, BK=64 ----
        for (int kb = 0; kb < 8; ++kb) {
            __syncthreads();
            // stage X chunk: 64 rows x 64 cols (fp32 -> bf16)
            {
                int g = tid;
                #pragma unroll
                for (int it = 0; it < 2; ++it, g += 256) {
                    int row = g >> 3, c8 = (g & 7) * 8;
                    cvt8_store(&L.st.x[row * 72 + c8],
                               &x[(size_t)(m0 + row) * HID + kb * 64 + c8]);
                }
            }
            // stage W chunk: 192 gathered rows (Q/K/V of head h) x 64 cols
            #pragma unroll
            for (int it = 0; it < 6; ++it) {
                int g = tid + it * 256;
                int n = g >> 3, c8 = (g & 7) * 8;
                int grow = (n >> 6) * HID + h * HDIM + (n & 63);
                if (use_bf)
                    *(short8*)&L.st.w[n * 72 + c8] =
                        *(const short8*)&wq_b[(size_t)grow * HID + kb * 64 + c8];
                else
                    cvt8_store(&L.st.w[n * 72 + c8],
                               &wq_f[(size_t)grow * HID + kb * 64 + c8]);
            }
            __syncthreads();
            #pragma unroll
            for (int ks = 0; ks < 2; ++ks) {
                const int ko = ks * 32 + q8;
                short8 a[4], b[3];
                #pragma unroll
                for (int fr = 0; fr < 4; ++fr)
                    a[fr] = *(const short8*)&L.st.x[(fr * 16 + ln) * 72 + ko];
                #pragma unroll
                for (int fc = 0; fc < 3; ++fc)
                    b[fc] = *(const short8*)&L.st.w[(wave * 48 + fc * 16 + ln) * 72 + ko];
                #pragma unroll
                for (int fr = 0; fr < 4; ++fr)
                    #pragma unroll
                    for (int fc = 0; fc < 3; ++fc)
                        acc[fr][fc] = mfma16(a[fr], b[fc], acc[fr][fc]);
            }
        }
        __syncthreads();   // staging region about to be reused as Q/K/VT/P

        // ---- epilogue: C frags -> LDS Q (x0.125) / K / V^T, bf16 ----
        #pragma unroll
        for (int fr = 0; fr < 4; ++fr) {
            #pragma unroll
            for (int fc = 0; fc < 3; ++fc) {
                const int c  = wave * 48 + fc * 16 + ln;   // branch is wave-uniform per frag
                const int mb = fr * 16 + qrow;
                const float4v v = acc[fr][fc];
                if (c < 64) {
                    #pragma unroll
                    for (int r = 0; r < 4; ++r)
                        L.at.q[(mb + r) * 72 + c] = bf16rne(v[r] * 0.125f);
                } else if (c < 128) {
                    #pragma unroll
                    for (int r = 0; r < 4; ++r)
                        L.at.k[(mb + r) * 72 + (c - 64)] = bf16rne(v[r]);
                } else {
                    #pragma unroll
                    for (int r = 0; r < 4; ++r)
                        L.at.vt[(c - 128) * 88 + (mb + r)] = bf16rne(v[r]);
                }
            }
        }
        // re-zero pads clobbered by staging: P keys 16..31, VT cols 64..87
        for (int i = tid; i < 4 * 16 * 16; i += 256) {
            int b = i >> 8, q = (i >> 4) & 15, key = 16 + (i & 15);
            L.at.p[b * 640 + q * 40 + key] = 0;
        }
        for (int i = tid; i < 64 * 24; i += 256) {
            int d = i / 24, c = 64 + (i % 24);
            L.at.vt[d * 88 + c] = 0;
        }
        __syncthreads();

        // ---- attention: wave w handles batch w (tile rows 16w..16w+15) ----
        {
            const int rb = wave * 16;
            const short* qp = &L.at.q[(rb + ln) * 72 + q8];
            const short* kp = &L.at.k[(rb + ln) * 72 + q8];
            short8 aq0 = *(const short8*)qp;
            short8 aq1 = *(const short8*)(qp + 32);
            short8 bk0 = *(const short8*)kp;
            short8 bk1 = *(const short8*)(kp + 32);
            float4v s = (float4v){0.f, 0.f, 0.f, 0.f};
            s = mfma16(aq0, bk0, s);
            s = mfma16(aq1, bk1, s);          // s[r] = score[q=qrow+r][key=ln] (pre-scaled)

            float4v mx = s;
            #pragma unroll
            for (int off = 1; off < 16; off <<= 1)
                #pragma unroll
                for (int r = 0; r < 4; ++r)
                    mx[r] = fmaxf(mx[r], __shfl_xor(mx[r], off));
            float4v p;
            #pragma unroll
            for (int r = 0; r < 4; ++r) p[r] = __expf(s[r] - mx[r]);
            float4v sm = p;
            #pragma unroll
            for (int off = 1; off < 16; off <<= 1)
                #pragma unroll
                for (int r = 0; r < 4; ++r)
                    sm[r] += __shfl_xor(sm[r], off);
            #pragma unroll
            for (int r = 0; r < 4; ++r) {
                float pi = p[r] * __builtin_amdgcn_rcpf(sm[r]);
                L.at.p[wave * 640 + (qrow + r) * 40 + ln] = bf16rne(pi);
            }
            // P (A-layout) @ V^T (B-layout), K=32 with zero-padded keys 16..31
            short8 ap = *(const short8*)&L.at.p[wave * 640 + ln * 40 + q8];
            #pragma unroll
            for (int dc = 0; dc < 4; ++dc) {
                short8 bv = *(const short8*)&L.at.vt[(dc * 16 + ln) * 88 + rb + q8];
                float4v o = (float4v){0.f, 0.f, 0.f, 0.f};
                o = mfma16(ap, bv, o);
                #pragma unroll
                for (int r = 0; r < 4; ++r)
                    out[(size_t)(m0 + rb + qrow + r) * HID + h * HDIM + dc * 16 + ln] = o[r];
            }
        }
    }
}

// ---------------- k2: out-proj in-place on d_out ----------------
// grid 1024 x 512 threads (8 waves). Block owns rows [64b, 64b+64), reads/writes only those.
__global__ __launch_bounds__(512, 2)
void oproj_kernel(float* __restrict__ io, const float* __restrict__ wo_f,
                  const short* __restrict__ wo_b, const int use_bf) {
    __shared__ __align__(16) short sA[64 * 40];     //  5120 B
    __shared__ __align__(16) short sW2[512 * 40];   // 40960 B

    const int tid  = threadIdx.x;
    const int wave = tid >> 6;
    const int lane = tid & 63;
    const int ln   = lane & 15;
    const int q8   = (lane >> 4) * 8;
    const int qrow = (lane >> 4) * 4;
    const int m0   = blockIdx.x * 64;

    float4v acc[4][4];
    #pragma unroll
    for (int fr = 0; fr < 4; ++fr)
        #pragma unroll
        for (int fc = 0; fc < 4; ++fc)
            acc[fr][fc] = (float4v){0.f, 0.f, 0.f, 0.f};

    for (int kb = 0; kb < 16; ++kb) {   // BK = 32
        __syncthreads();
        if (tid < 256) {                // stage attn chunk 64x32 (fp32 -> bf16)
            int row = tid >> 2, c8 = (tid & 3) * 8;
            cvt8_store(&sA[row * 40 + c8],
                       &io[(size_t)(m0 + row) * HID + kb * 32 + c8]);
        }
        #pragma unroll
        for (int it = 0; it < 4; ++it) { // stage w_o chunk 512x32
            int g = tid + it * 512;
            int n = g >> 2, c8 = (g & 3) * 8;
            if (use_bf)
                *(short8*)&sW2[n * 40 + c8] =
                    *(const short8*)&wo_b[(size_t)n * HID + kb * 32 + c8];
            else
                cvt8_store(&sW2[n * 40 + c8], &wo_f[(size_t)n * HID + kb * 32 + c8]);
        }
        __syncthreads();
        short8 a[4], b[4];
        #pragma unroll
        for (int fr = 0; fr < 4; ++fr)
            a[fr] = *(const short8*)&sA[(fr * 16 + ln) * 40 + q8];
        #pragma unroll
        for (int fc = 0; fc < 4; ++fc)
            b[fc] = *(const short8*)&sW2[(wave * 64 + fc * 16 + ln) * 40 + q8];
        #pragma unroll
        for (int fr = 0; fr < 4; ++fr)
            #pragma unroll
            for (int fc = 0; fc < 4; ++fc)
                acc[fr][fc] = mfma16(a[fr], b[fc], acc[fr][fc]);
    }
    // all staging reads of this block's rows are complete (last barrier) -> safe overwrite
    #pragma unroll
    for (int fr = 0; fr < 4; ++fr)
        #pragma unroll
        for (int fc = 0; fc < 4; ++fc)
            #pragma unroll
            for (int r = 0; r < 4; ++r)
                io[(size_t)(m0 + fr * 16 + qrow + r) * HID + wave * 64 + fc * 16 + ln] =
                    acc[fr][fc][r];
}

extern "C" void kernel_launch(void* const* d_in, const int* in_sizes, int n_in,
                              void* d_out, int out_size, void* d_ws, size_t ws_size,
                              hipStream_t stream) {
    const float* x    = (const float*)d_in[0];
    const float* wqkv = (const float*)d_in[1];
    const float* wo   = (const float*)d_in[2];
    float* out = (float*)d_out;

    const size_t need = (size_t)(786432 + 262144) * 2;  // 2 MB bf16 weights
    const int use_bf = (d_ws != nullptr && ws_size >= need) ? 1 : 0;
    short* wb = (short*)d_ws;

    if (use_bf)
        cvt_w_kernel<<<1024, 256, 0, stream>>>(wqkv, wo, wb);

    qkv_attn_kernel<<<1024, 256, 0, stream>>>(
        x, wqkv, use_bf ? wb : nullptr, use_bf, out);

    oproj_kernel<<<1024, 512, 0, stream>>>(
        out, wo, use_bf ? (wb + 786432) : nullptr, use_bf);
}